// Round 3
// baseline (24078.825 us; speedup 1.0000x reference)
//
#include <hip/hip_runtime.h>
#include <math.h>

// Spectral regularization: 1e-4 * (sigma_max(w1) + sigma_max(w2) + sigma_max(w3))
// Lanczos (K steps, no reorth) on B = A^T A with bf16 matrices (L3-resident).
// One fused kernel per step: block stages a 32KB row-chunk in LDS, computes
// w = A_chunk v, then z += A_chunk^T w from LDS (single pass over A per step).
// Last block per matrix performs the alpha/beta update in-kernel.
//
// Shapes (row-major): w1 4096x4096, w2 8192x2048, w3 2048x8192 (each 16777216)

#define K_STEPS 32
#define VCAP 8192
#define MELEMS 16777216
#define NBLK_PER_MAT 1024

typedef unsigned int u32;

__device__ __forceinline__ int matN(int m) { return m == 0 ? 4096 : (m == 1 ? 2048 : 8192); }

__device__ __forceinline__ float bflo(u32 u) { return __uint_as_float(u << 16); }
__device__ __forceinline__ float bfhi(u32 u) { return __uint_as_float(u & 0xffff0000u); }

__device__ __forceinline__ unsigned short bf_rne(float f) {
    u32 u = __float_as_uint(f);
    u32 r = u + 0x7fffu + ((u >> 16) & 1u);
    return (unsigned short)(r >> 16);
}

// vec layout (floats):
//  [0*VCAP) V0 (3*VCAP) | [3*VCAP) V1 (3*VCAP) | [6*VCAP) W (3*VCAP, fallback only)
//  [9*VCAP) Z (3*VCAP)  | [12*VCAP) ALPHA(3K), BETA(3K), CNT(3 ints)

__device__ float blockReduce(float v) {
    __shared__ float sh[16];
    int lane = threadIdx.x & 63, wid = threadIdx.x >> 6;
#pragma unroll
    for (int off = 32; off; off >>= 1) v += __shfl_down(v, off, 64);
    if (lane == 0) sh[wid] = v;
    __syncthreads();
    if (wid == 0) {
        int nw = (blockDim.x + 63) >> 6;
        float x = (lane < nw) ? sh[lane] : 0.0f;
#pragma unroll
        for (int off = 8; off; off >>= 1) x += __shfl_down(x, off, 64);
        if (lane == 0) sh[0] = x;
    }
    __syncthreads();
    float r = sh[0];
    __syncthreads();
    return r;
}

__global__ __launch_bounds__(1024) void k_init(float* vec) {
    int mat = blockIdx.x;
    int n = matN(mat);
    float* V0 = vec + mat * VCAP;
    float* V1 = vec + 3 * VCAP + mat * VCAP;
    float* Z  = vec + 9 * VCAP + mat * VCAP;
    int tid = threadIdx.x;
    float acc = 0.0f;
    for (int i = tid; i < VCAP; i += 1024) {
        float val = 0.0f;
        if (i < n) {
            unsigned h = (unsigned)(i * 2654435761u) ^ (0x9E3779B9u * (unsigned)(mat + 1));
            h ^= h >> 16; h *= 0x85EBCA6Bu; h ^= h >> 13; h *= 0xC2B2AE35u; h ^= h >> 16;
            val = ((h >> 8) * (1.0f / 16777216.0f)) - 0.5f;
            acc += val * val;
        }
        V1[i] = val; V0[i] = 0.0f; Z[i] = 0.0f;
    }
    float nrm2 = blockReduce(acc);
    float inv = rsqrtf(nrm2);
    for (int i = tid; i < n; i += 1024) V1[i] *= inv;
    if (tid == 0) ((int*)(vec + 12 * VCAP + 6 * K_STEPS))[mat] = 0;
}

__global__ __launch_bounds__(256) void k_convert(const float* __restrict__ A0,
                                                 const float* __restrict__ A1,
                                                 const float* __restrict__ A2,
                                                 unsigned short* __restrict__ B) {
    int mat = blockIdx.y;
    const float* A = mat == 0 ? A0 : (mat == 1 ? A1 : A2);
    unsigned short* Bm = B + (size_t)mat * MELEMS;
    int stride = gridDim.x * blockDim.x;
    const int nvec = MELEMS / 4;
    for (int i = blockIdx.x * blockDim.x + threadIdx.x; i < nvec; i += stride) {
        float4 a = ((const float4*)A)[i];
        ushort4 o;
        o.x = bf_rne(a.x); o.y = bf_rne(a.y); o.z = bf_rne(a.z); o.w = bf_rne(a.w);
        ((ushort4*)Bm)[i] = o;
    }
}

// ---- fused Lanczos step: one block = R rows x N cols tile (32KB bf16 in LDS) ----
// Phase 1: stage tile to LDS, compute w_r = <A_row, v> (wave-per-row dot).
// Phase 2: z[c] += sum_r tile[r][c] * w_r, atomically accumulated to global Z.
// Last block of the matrix: alpha/beta update, normalize, zero Z, reset counter.
template <int N, int R>
__device__ void fused_body(const unsigned short* __restrict__ Am,
                           float* __restrict__ vec, int mat, int chunk, int j,
                           uint4* tile4, float* w_p, int* last_p) {
    constexpr int NU4 = N >> 3;   // uint4 per row
    constexpr int NK  = N >> 11;  // uint4 per thread (phase 2)
    const int tid = threadIdx.x;
    const int wid = tid >> 6, lane = tid & 63;
    const int r0 = chunk * R;
    const float4* vp = (const float4*)(vec + 3 * VCAP + mat * VCAP);
    float* Zm = vec + 9 * VCAP + mat * VCAP;

    // ---- phase 1 ----
    if constexpr (R == 2) {
        if (tid < 2) w_p[tid] = 0.0f;
        __syncthreads();
        int r_local = wid & 1;
        int half = wid >> 1;
        const uint4* rp = (const uint4*)(Am + (size_t)(r0 + r_local) * N);
        int tstart = half * (NU4 / 2);
        float s = 0.0f;
#pragma unroll
        for (int t = lane + tstart; t < tstart + NU4 / 2; t += 64) {
            uint4 a = rp[t];
            tile4[r_local * NU4 + t] = a;
            float4 v0 = vp[2 * t], v1 = vp[2 * t + 1];
            s += bflo(a.x) * v0.x + bfhi(a.x) * v0.y + bflo(a.y) * v0.z + bfhi(a.y) * v0.w
               + bflo(a.z) * v1.x + bfhi(a.z) * v1.y + bflo(a.w) * v1.z + bfhi(a.w) * v1.w;
        }
#pragma unroll
        for (int off = 32; off; off >>= 1) s += __shfl_down(s, off, 64);
        if (lane == 0) atomicAdd(&w_p[r_local], s);
        __syncthreads();
    } else {
        constexpr int RPW = R / 4;
#pragma unroll
        for (int rr = 0; rr < RPW; ++rr) {
            int r_local = wid * RPW + rr;
            const uint4* rp = (const uint4*)(Am + (size_t)(r0 + r_local) * N);
            float s = 0.0f;
#pragma unroll
            for (int t = lane; t < NU4; t += 64) {
                uint4 a = rp[t];
                tile4[r_local * NU4 + t] = a;
                float4 v0 = vp[2 * t], v1 = vp[2 * t + 1];
                s += bflo(a.x) * v0.x + bfhi(a.x) * v0.y + bflo(a.y) * v0.z + bfhi(a.y) * v0.w
                   + bflo(a.z) * v1.x + bfhi(a.z) * v1.y + bflo(a.w) * v1.z + bfhi(a.w) * v1.w;
            }
#pragma unroll
            for (int off = 32; off; off >>= 1) s += __shfl_down(s, off, 64);
            if (lane == 0) w_p[r_local] = s;
        }
        __syncthreads();
    }

    // ---- phase 2 ----
    float accx[NK * 8];
#pragma unroll
    for (int i = 0; i < NK * 8; ++i) accx[i] = 0.0f;
#pragma unroll
    for (int r = 0; r < R; ++r) {
        float w = w_p[r];
#pragma unroll
        for (int k = 0; k < NK; ++k) {
            uint4 a = tile4[r * NU4 + tid + (k << 8)];
            accx[k * 8 + 0] += bflo(a.x) * w; accx[k * 8 + 1] += bfhi(a.x) * w;
            accx[k * 8 + 2] += bflo(a.y) * w; accx[k * 8 + 3] += bfhi(a.y) * w;
            accx[k * 8 + 4] += bflo(a.z) * w; accx[k * 8 + 5] += bfhi(a.z) * w;
            accx[k * 8 + 6] += bflo(a.w) * w; accx[k * 8 + 7] += bfhi(a.w) * w;
        }
    }
#pragma unroll
    for (int k = 0; k < NK; ++k) {
        int base = (tid + (k << 8)) << 3;
#pragma unroll
        for (int i = 0; i < 8; ++i) atomicAdd(&Zm[base + i], accx[k * 8 + i]);
    }

    // ---- last-block update ----
    __syncthreads();      // barrier drains this block's atomics (vmcnt 0)
    __threadfence();
    int* cnt = (int*)(vec + 12 * VCAP + 6 * K_STEPS);
    if (tid == 0) {
        int old = atomicAdd(&cnt[mat], 1);
        *last_p = (old == NBLK_PER_MAT - 1);
    }
    __syncthreads();
    if (!*last_p) return;

    float* V0 = vec + mat * VCAP;
    float* V1 = vec + 3 * VCAP + mat * VCAP;
    float* ALPHA = vec + 12 * VCAP;
    float* BETA  = ALPHA + 3 * K_STEPS;

    float acc = 0.0f;
    for (int i = tid; i < N; i += 256) acc += V1[i] * Zm[i];
    float alpha = blockReduce(acc);
    float bp = (j > 0) ? BETA[mat * K_STEPS + j - 1] : 0.0f;
    float acc2 = 0.0f;
    for (int i = tid; i < N; i += 256) {
        float v1 = V1[i];
        float r = Zm[i] - alpha * v1 - bp * V0[i];
        V0[i] = v1;
        Zm[i] = r;
        acc2 += r * r;
    }
    float b2 = blockReduce(acc2);
    float beta = sqrtf(b2);
    float inv = (beta > 1e-20f) ? (1.0f / beta) : 0.0f;
    for (int i = tid; i < N; i += 256) {
        V1[i] = Zm[i] * inv;
        Zm[i] = 0.0f;
    }
    if (tid == 0) {
        ALPHA[mat * K_STEPS + j] = alpha;
        BETA[mat * K_STEPS + j] = beta;
        cnt[mat] = 0;
    }
}

__global__ __launch_bounds__(256) void k_fused(const unsigned short* __restrict__ B,
                                               float* __restrict__ vec, int j) {
    __shared__ uint4 tile4[2048];   // 32 KB
    __shared__ float w_p[16];
    __shared__ int last_p;
    int bid = blockIdx.x;
    int mat = bid >> 10;            // 1024 blocks per matrix
    int chunk = bid & 1023;
    const unsigned short* Am = B + (size_t)mat * MELEMS;
    if (mat == 0)      fused_body<4096, 4>(Am, vec, 0, chunk, j, tile4, w_p, &last_p);
    else if (mat == 1) fused_body<2048, 8>(Am, vec, 1, chunk, j, tile4, w_p, &last_p);
    else               fused_body<8192, 2>(Am, vec, 2, chunk, j, tile4, w_p, &last_p);
}

// ---------------- fp32 fallback path (ws too small for bf16 copy) ----------------
__global__ __launch_bounds__(256) void k_gemvA(const float* __restrict__ A0,
                                               const float* __restrict__ A1,
                                               const float* __restrict__ A2,
                                               float* __restrict__ vec) {
    const float* V1 = vec + 3 * VCAP;
    float* W = vec + 6 * VCAP;
    int wid = (int)((blockIdx.x * blockDim.x + threadIdx.x) >> 6);
    int lane = threadIdx.x & 63;
    int mat, row;
    if (wid < 4096)       { mat = 0; row = wid; }
    else if (wid < 12288) { mat = 1; row = wid - 4096; }
    else                  { mat = 2; row = wid - 12288; }
    const float* A = mat == 0 ? A0 : (mat == 1 ? A1 : A2);
    int n = matN(mat);
    const float4* rowp = (const float4*)(A + (size_t)row * n);
    const float4* vp = (const float4*)(V1 + mat * VCAP);
    int nf4 = n >> 2;
    float s = 0.0f;
    for (int t = lane; t < nf4; t += 64) {
        float4 a = rowp[t], v = vp[t];
        s += a.x * v.x + a.y * v.y + a.z * v.z + a.w * v.w;
    }
#pragma unroll
    for (int off = 32; off; off >>= 1) s += __shfl_down(s, off, 64);
    if (lane == 0) W[mat * VCAP + row] = s;
}

__global__ __launch_bounds__(256) void k_gemvT(const float* __restrict__ A0,
                                               const float* __restrict__ A1,
                                               const float* __restrict__ A2,
                                               float* __restrict__ vec) {
    const float* W = vec + 6 * VCAP;
    float* Z = vec + 9 * VCAP;
    int bid = blockIdx.x;
    int mat = bid >> 8;
    int t = bid & 255;
    int n = matN(mat);
    int nColTiles = n >> 10;
    int colTile = t % nColTiles;
    int rowChunk = t / nColTiles;
    int r0 = rowChunk * 64;
    int col = colTile * 1024 + threadIdx.x * 4;
    const float* A = mat == 0 ? A0 : (mat == 1 ? A1 : A2);
    __shared__ float wsh[64];
    if (threadIdx.x < 64) wsh[threadIdx.x] = W[mat * VCAP + r0 + threadIdx.x];
    __syncthreads();
    const float* Ab = A + (size_t)r0 * n + col;
    float4 s = {0.0f, 0.0f, 0.0f, 0.0f};
#pragma unroll 4
    for (int r = 0; r < 64; ++r) {
        float4 a = *(const float4*)(Ab + (size_t)r * n);
        float w = wsh[r];
        s.x += a.x * w; s.y += a.y * w; s.z += a.z * w; s.w += a.w * w;
    }
    float* Zm = Z + mat * VCAP + col;
    atomicAdd(Zm + 0, s.x);
    atomicAdd(Zm + 1, s.y);
    atomicAdd(Zm + 2, s.z);
    atomicAdd(Zm + 3, s.w);
}

__global__ __launch_bounds__(1024) void k_update(float* __restrict__ vec, int j) {
    int mat = blockIdx.x;
    int n = matN(mat);
    float* V0 = vec + mat * VCAP;
    float* V1 = vec + 3 * VCAP + mat * VCAP;
    float* Z  = vec + 9 * VCAP + mat * VCAP;
    float* ALPHA = vec + 12 * VCAP;
    float* BETA  = ALPHA + 3 * K_STEPS;
    int tid = threadIdx.x;
    float acc = 0.0f;
    for (int i = tid; i < n; i += 1024) acc += V1[i] * Z[i];
    float alpha = blockReduce(acc);
    float bp = (j > 0) ? BETA[mat * K_STEPS + j - 1] : 0.0f;
    float acc2 = 0.0f;
    for (int i = tid; i < n; i += 1024) {
        float v1 = V1[i];
        float r = Z[i] - alpha * v1 - bp * V0[i];
        V0[i] = v1;
        Z[i] = r;
        acc2 += r * r;
    }
    float b2 = blockReduce(acc2);
    float beta = sqrtf(b2);
    float inv = (beta > 1e-20f) ? (1.0f / beta) : 0.0f;
    for (int i = tid; i < n; i += 1024) {
        V1[i] = Z[i] * inv;
        Z[i] = 0.0f;
    }
    if (tid == 0) {
        ALPHA[mat * K_STEPS + j] = alpha;
        BETA[mat * K_STEPS + j] = beta;
    }
}

// lambda_max of each KxK tridiagonal: 64-lane parallel Sturm bisection per matrix.
__global__ __launch_bounds__(256) void k_final2(const float* __restrict__ vec,
                                                float* __restrict__ out) {
    __shared__ double sa[3][K_STEPS], sb[3][K_STEPS];
    __shared__ double sig[3];
    int tid = threadIdx.x, wid = tid >> 6, lane = tid & 63;
    if (wid < 3 && lane < K_STEPS) {
        const float* AL = vec + 12 * VCAP + wid * K_STEPS;
        const float* BE = vec + 12 * VCAP + 3 * K_STEPS + wid * K_STEPS;
        sa[wid][lane] = (double)AL[lane];
        sb[wid][lane] = (lane < K_STEPS - 1) ? (double)BE[lane] : 0.0;
    }
    __syncthreads();
    if (wid < 3) {
        double g = 0.0;
        if (lane < K_STEPS) {
            double bl_ = lane ? sb[wid][lane - 1] : 0.0;
            g = sa[wid][lane] + bl_ + sb[wid][lane];
        }
#pragma unroll
        for (int off = 32; off; off >>= 1) {
            double o = __shfl_xor(g, off, 64);
            if (o > g) g = o;
        }
        double lo = 0.0, hi = g > 0.0 ? g : 1.0;
        for (int round = 0; round < 4; ++round) {
            double step = (hi - lo) / 65.0;
            double x = lo + step * (double)(lane + 1);
            int cnt = 0;
            double d = 1.0;
            for (int i = 0; i < K_STEPS; ++i) {
                double off2 = 0.0;
                if (i) { double b = sb[wid][i - 1]; off2 = b * b / d; }
                d = (sa[wid][i] - x) - off2;
                if (d == 0.0) d = -1e-300;
                if (d < 0.0) cnt++;
            }
            unsigned long long mask = __ballot(cnt >= K_STEPS);
            if (mask) {
                int idx = __ffsll(mask) - 1;
                hi = lo + step * (double)(idx + 1);
                lo = lo + step * (double)idx;
            } else {
                lo = lo + step * 64.0;
            }
        }
        if (lane == 0) {
            double lam = 0.5 * (lo + hi);
            sig[wid] = sqrt(lam > 0.0 ? lam : 0.0);
        }
    }
    __syncthreads();
    if (tid == 0) out[0] = (float)(1e-4 * (sig[0] + sig[1] + sig[2]));
}

extern "C" void kernel_launch(void* const* d_in, const int* in_sizes, int n_in,
                              void* d_out, int out_size, void* d_ws, size_t ws_size,
                              hipStream_t stream) {
    const float* A0 = (const float*)d_in[0];
    const float* A1 = (const float*)d_in[1];
    const float* A2 = (const float*)d_in[2];
    float* out = (float*)d_out;

    const size_t bf_bytes = (size_t)3 * MELEMS * 2;
    const size_t vec_bytes = (size_t)(12 * VCAP + 6 * K_STEPS + 4) * 4;
    bool use_bf = ws_size >= bf_bytes + vec_bytes;

    unsigned short* B = (unsigned short*)d_ws;
    float* vec = use_bf ? (float*)((char*)d_ws + bf_bytes) : (float*)d_ws;

    hipLaunchKernelGGL(k_init, dim3(3), dim3(1024), 0, stream, vec);
    if (use_bf) {
        hipLaunchKernelGGL(k_convert, dim3(4096, 3), dim3(256), 0, stream, A0, A1, A2, B);
        for (int j = 0; j < K_STEPS; ++j) {
            hipLaunchKernelGGL(k_fused, dim3(3 * NBLK_PER_MAT), dim3(256), 0, stream, B, vec, j);
        }
    } else {
        for (int j = 0; j < K_STEPS; ++j) {
            hipLaunchKernelGGL(k_gemvA, dim3(3584), dim3(256), 0, stream, A0, A1, A2, vec);
            hipLaunchKernelGGL(k_gemvT, dim3(768), dim3(256), 0, stream, A0, A1, A2, vec);
            hipLaunchKernelGGL(k_update, dim3(3), dim3(1024), 0, stream, vec, j);
        }
    }
    hipLaunchKernelGGL(k_final2, dim3(1), dim3(256), 0, stream, vec, out);
}

// Round 4
// 1858.728 us; speedup vs baseline: 12.9545x; 12.9545x over previous
//
#include <hip/hip_runtime.h>
#include <math.h>

// Spectral regularization: 1e-4 * (sigma_max(w1) + sigma_max(w2) + sigma_max(w3))
// Lanczos (K=32, no reorth) on B = A^T A with bf16 matrices (L3-resident).
// Per step: k_stepA (w = A v), k_stepT (z-partials, NO atomics), k_redupd
// (reduce partials + alpha/beta update). Then parallel Sturm bisection.
//
// Shapes (row-major): w1 4096x4096, w2 8192x2048, w3 2048x8192 (each 16777216)

#define K_STEPS 32
#define VCAP 8192
#define MELEMS 16777216
#define POFF (12 * VCAP)            // partials: 3 x 262144 floats
#define PSZ 262144
#define AOFF (POFF + 3 * PSZ)       // ALPHA(3K), BETA(3K)

typedef unsigned int u32;
typedef unsigned short u16;

__device__ __forceinline__ int matN(int m) { return m == 0 ? 4096 : (m == 1 ? 2048 : 8192); }

__device__ __forceinline__ float bflo(u32 u) { return __uint_as_float(u << 16); }
__device__ __forceinline__ float bfhi(u32 u) { return __uint_as_float(u & 0xffff0000u); }

__device__ __forceinline__ u32 bf_rne(float f) {
    u32 u = __float_as_uint(f);
    return (u + 0x7fffu + ((u >> 16) & 1u)) >> 16;
}

__device__ float blockReduce(float v) {
    __shared__ float sh[16];
    int lane = threadIdx.x & 63, wid = threadIdx.x >> 6;
#pragma unroll
    for (int off = 32; off; off >>= 1) v += __shfl_down(v, off, 64);
    if (lane == 0) sh[wid] = v;
    __syncthreads();
    if (wid == 0) {
        int nw = (blockDim.x + 63) >> 6;
        float x = (lane < nw) ? sh[lane] : 0.0f;
#pragma unroll
        for (int off = 8; off; off >>= 1) x += __shfl_down(x, off, 64);
        if (lane == 0) sh[0] = x;
    }
    __syncthreads();
    float r = sh[0];
    __syncthreads();
    return r;
}

__global__ __launch_bounds__(1024) void k_init(float* vec) {
    int mat = blockIdx.x;
    int n = matN(mat);
    float* V0 = vec + mat * VCAP;
    float* V1 = vec + 3 * VCAP + mat * VCAP;
    float* Z  = vec + 9 * VCAP + mat * VCAP;   // fallback path only
    int tid = threadIdx.x;
    float acc = 0.0f;
    for (int i = tid; i < VCAP; i += 1024) {
        float val = 0.0f;
        if (i < n) {
            unsigned h = (unsigned)(i * 2654435761u) ^ (0x9E3779B9u * (unsigned)(mat + 1));
            h ^= h >> 16; h *= 0x85EBCA6Bu; h ^= h >> 13; h *= 0xC2B2AE35u; h ^= h >> 16;
            val = ((h >> 8) * (1.0f / 16777216.0f)) - 0.5f;
            acc += val * val;
        }
        V1[i] = val; V0[i] = 0.0f; Z[i] = 0.0f;
    }
    float nrm2 = blockReduce(acc);
    float inv = rsqrtf(nrm2);
    for (int i = tid; i < n; i += 1024) V1[i] *= inv;
}

// fp32 -> bf16, 16B-wide stores
__global__ __launch_bounds__(256) void k_convert(const float* __restrict__ A0,
                                                 const float* __restrict__ A1,
                                                 const float* __restrict__ A2,
                                                 u16* __restrict__ B) {
    int mat = blockIdx.y;
    const float* A = mat == 0 ? A0 : (mat == 1 ? A1 : A2);
    u16* Bm = B + (size_t)mat * MELEMS;
    int stride = gridDim.x * blockDim.x;
    const int nvec = MELEMS / 8;
    for (int i = blockIdx.x * blockDim.x + threadIdx.x; i < nvec; i += stride) {
        float4 a = ((const float4*)A)[2 * i];
        float4 b = ((const float4*)A)[2 * i + 1];
        uint4 o;
        o.x = bf_rne(a.x) | (bf_rne(a.y) << 16);
        o.y = bf_rne(a.z) | (bf_rne(a.w) << 16);
        o.z = bf_rne(b.x) | (bf_rne(b.y) << 16);
        o.w = bf_rne(b.z) | (bf_rne(b.w) << 16);
        ((uint4*)Bm)[i] = o;
    }
}

// ---- w = A v : one wave per row ----
__global__ __launch_bounds__(256) void k_stepA(const u16* __restrict__ B,
                                               float* __restrict__ vec) {
    const float* V1 = vec + 3 * VCAP;
    float* W = vec + 6 * VCAP;
    int wid = (int)((blockIdx.x * blockDim.x + threadIdx.x) >> 6);
    int lane = threadIdx.x & 63;
    int mat, row;
    if (wid < 4096)       { mat = 0; row = wid; }
    else if (wid < 12288) { mat = 1; row = wid - 4096; }
    else                  { mat = 2; row = wid - 12288; }
    int n = matN(mat);
    const uint4* rp = (const uint4*)(B + (size_t)mat * MELEMS + (size_t)row * n);
    const float4* vp = (const float4*)(V1 + mat * VCAP);
    int nu = n >> 3;
    float s = 0.0f;
    for (int t = lane; t < nu; t += 64) {
        uint4 a = rp[t];
        float4 v0 = vp[2 * t], v1 = vp[2 * t + 1];
        s += bflo(a.x) * v0.x + bfhi(a.x) * v0.y + bflo(a.y) * v0.z + bfhi(a.y) * v0.w
           + bflo(a.z) * v1.x + bfhi(a.z) * v1.y + bflo(a.w) * v1.z + bfhi(a.w) * v1.w;
    }
#pragma unroll
    for (int off = 32; off; off >>= 1) s += __shfl_down(s, off, 64);
    if (lane == 0) W[mat * VCAP + row] = s;
}

// ---- z-partials: block = 64 rows x 2048 cols, private partial slice, no atomics ----
// grid 384: [0,128) mat0 (RC=64, 2 colTiles); [128,256) mat1 (RC=128, 1); [256,384) mat2 (RC=32, 4)
__global__ __launch_bounds__(256) void k_stepT(const u16* __restrict__ B,
                                               float* __restrict__ vec) {
    int bid = blockIdx.x;
    int mat, rc, ct, n;
    if (bid < 128)      { mat = 0; n = 4096; rc = bid >> 1;         ct = bid & 1; }
    else if (bid < 256) { mat = 1; n = 2048; rc = bid - 128;        ct = 0; }
    else                { mat = 2; n = 8192; rc = (bid - 256) >> 2; ct = (bid - 256) & 3; }
    int r0 = rc * 64;
    int col = ct * 2048 + threadIdx.x * 8;
    __shared__ float wsh[64];
    if (threadIdx.x < 64) wsh[threadIdx.x] = vec[6 * VCAP + mat * VCAP + r0 + threadIdx.x];
    __syncthreads();
    const u16* Ab = B + (size_t)mat * MELEMS + (size_t)r0 * n + col;
    float s0 = 0, s1 = 0, s2 = 0, s3 = 0, s4 = 0, s5 = 0, s6 = 0, s7 = 0;
#pragma unroll 8
    for (int r = 0; r < 64; ++r) {
        uint4 a = *(const uint4*)(Ab + (size_t)r * n);
        float w = wsh[r];
        s0 += bflo(a.x) * w; s1 += bfhi(a.x) * w;
        s2 += bflo(a.y) * w; s3 += bfhi(a.y) * w;
        s4 += bflo(a.z) * w; s5 += bfhi(a.z) * w;
        s6 += bflo(a.w) * w; s7 += bfhi(a.w) * w;
    }
    float* P = vec + POFF + mat * PSZ + (size_t)rc * n + col;
    float4 lo = {s0, s1, s2, s3}, hi = {s4, s5, s6, s7};
    ((float4*)P)[0] = lo;
    ((float4*)P)[1] = hi;
}

// ---- reduce partials + alpha/beta update, one 1024-thread block per matrix ----
template <int N, int RC, int NPER>
__device__ void red_upd(float* __restrict__ vec, int mat, int j) {
    const float* P = vec + POFF + mat * PSZ;
    float* V0 = vec + mat * VCAP;
    float* V1 = vec + 3 * VCAP + mat * VCAP;
    float* ALPHA = vec + AOFF;
    float* BETA  = ALPHA + 3 * K_STEPS;
    int tid = threadIdx.x;

    float z[NPER], v1r[NPER], v0r[NPER];
#pragma unroll
    for (int e = 0; e < NPER; ++e) {
        int i = tid + e * 1024;
        float s = 0.0f;
#pragma unroll 8
        for (int rc = 0; rc < RC; ++rc) s += P[(size_t)rc * N + i];
        z[e] = s;
        v1r[e] = V1[i];
        v0r[e] = V0[i];
    }
    float acc = 0.0f;
#pragma unroll
    for (int e = 0; e < NPER; ++e) acc += v1r[e] * z[e];
    float alpha = blockReduce(acc);

    float bp = (j > 0) ? BETA[mat * K_STEPS + j - 1] : 0.0f;
    float acc2 = 0.0f;
#pragma unroll
    for (int e = 0; e < NPER; ++e) {
        float r = z[e] - alpha * v1r[e] - bp * v0r[e];
        z[e] = r;
        acc2 += r * r;
    }
    float b2 = blockReduce(acc2);
    float beta = sqrtf(b2);
    float inv = (beta > 1e-20f) ? (1.0f / beta) : 0.0f;
#pragma unroll
    for (int e = 0; e < NPER; ++e) {
        int i = tid + e * 1024;
        V0[i] = v1r[e];
        V1[i] = z[e] * inv;
    }
    if (tid == 0) {
        ALPHA[mat * K_STEPS + j] = alpha;
        BETA[mat * K_STEPS + j] = beta;
    }
}

__global__ __launch_bounds__(1024) void k_redupd(float* __restrict__ vec, int j) {
    int mat = blockIdx.x;
    if (mat == 0)      red_upd<4096, 64, 4>(vec, 0, j);
    else if (mat == 1) red_upd<2048, 128, 2>(vec, 1, j);
    else               red_upd<8192, 32, 8>(vec, 2, j);
}

// ---------------- fp32 fallback path (ws too small for bf16 copy) ----------------
__global__ __launch_bounds__(256) void k_gemvA(const float* __restrict__ A0,
                                               const float* __restrict__ A1,
                                               const float* __restrict__ A2,
                                               float* __restrict__ vec) {
    const float* V1 = vec + 3 * VCAP;
    float* W = vec + 6 * VCAP;
    int wid = (int)((blockIdx.x * blockDim.x + threadIdx.x) >> 6);
    int lane = threadIdx.x & 63;
    int mat, row;
    if (wid < 4096)       { mat = 0; row = wid; }
    else if (wid < 12288) { mat = 1; row = wid - 4096; }
    else                  { mat = 2; row = wid - 12288; }
    const float* A = mat == 0 ? A0 : (mat == 1 ? A1 : A2);
    int n = matN(mat);
    const float4* rowp = (const float4*)(A + (size_t)row * n);
    const float4* vp = (const float4*)(V1 + mat * VCAP);
    int nf4 = n >> 2;
    float s = 0.0f;
    for (int t = lane; t < nf4; t += 64) {
        float4 a = rowp[t], v = vp[t];
        s += a.x * v.x + a.y * v.y + a.z * v.z + a.w * v.w;
    }
#pragma unroll
    for (int off = 32; off; off >>= 1) s += __shfl_down(s, off, 64);
    if (lane == 0) W[mat * VCAP + row] = s;
}

__global__ __launch_bounds__(256) void k_gemvT(const float* __restrict__ A0,
                                               const float* __restrict__ A1,
                                               const float* __restrict__ A2,
                                               float* __restrict__ vec) {
    const float* W = vec + 6 * VCAP;
    float* Z = vec + 9 * VCAP;
    int bid = blockIdx.x;
    int mat = bid >> 8;
    int t = bid & 255;
    int n = matN(mat);
    int nColTiles = n >> 10;
    int colTile = t % nColTiles;
    int rowChunk = t / nColTiles;
    int r0 = rowChunk * 64;
    int col = colTile * 1024 + threadIdx.x * 4;
    const float* A = mat == 0 ? A0 : (mat == 1 ? A1 : A2);
    __shared__ float wsh[64];
    if (threadIdx.x < 64) wsh[threadIdx.x] = W[mat * VCAP + r0 + threadIdx.x];
    __syncthreads();
    const float* Ab = A + (size_t)r0 * n + col;
    float4 s = {0.0f, 0.0f, 0.0f, 0.0f};
#pragma unroll 4
    for (int r = 0; r < 64; ++r) {
        float4 a = *(const float4*)(Ab + (size_t)r * n);
        float w = wsh[r];
        s.x += a.x * w; s.y += a.y * w; s.z += a.z * w; s.w += a.w * w;
    }
    float* Zm = Z + mat * VCAP + col;
    atomicAdd(Zm + 0, s.x);
    atomicAdd(Zm + 1, s.y);
    atomicAdd(Zm + 2, s.z);
    atomicAdd(Zm + 3, s.w);
}

__global__ __launch_bounds__(1024) void k_update(float* __restrict__ vec, int j) {
    int mat = blockIdx.x;
    int n = matN(mat);
    float* V0 = vec + mat * VCAP;
    float* V1 = vec + 3 * VCAP + mat * VCAP;
    float* Z  = vec + 9 * VCAP + mat * VCAP;
    float* ALPHA = vec + AOFF;
    float* BETA  = ALPHA + 3 * K_STEPS;
    int tid = threadIdx.x;
    float acc = 0.0f;
    for (int i = tid; i < n; i += 1024) acc += V1[i] * Z[i];
    float alpha = blockReduce(acc);
    float bp = (j > 0) ? BETA[mat * K_STEPS + j - 1] : 0.0f;
    float acc2 = 0.0f;
    for (int i = tid; i < n; i += 1024) {
        float v1 = V1[i];
        float r = Z[i] - alpha * v1 - bp * V0[i];
        V0[i] = v1;
        Z[i] = r;
        acc2 += r * r;
    }
    float b2 = blockReduce(acc2);
    float beta = sqrtf(b2);
    float inv = (beta > 1e-20f) ? (1.0f / beta) : 0.0f;
    for (int i = tid; i < n; i += 1024) {
        V1[i] = Z[i] * inv;
        Z[i] = 0.0f;
    }
    if (tid == 0) {
        ALPHA[mat * K_STEPS + j] = alpha;
        BETA[mat * K_STEPS + j] = beta;
    }
}

// lambda_max of each KxK tridiagonal: 64-lane parallel Sturm bisection per matrix.
__global__ __launch_bounds__(256) void k_final2(const float* __restrict__ vec,
                                                float* __restrict__ out) {
    __shared__ double sa[3][K_STEPS], sb[3][K_STEPS];
    __shared__ double sig[3];
    int tid = threadIdx.x, wid = tid >> 6, lane = tid & 63;
    if (wid < 3 && lane < K_STEPS) {
        const float* AL = vec + AOFF + wid * K_STEPS;
        const float* BE = vec + AOFF + 3 * K_STEPS + wid * K_STEPS;
        sa[wid][lane] = (double)AL[lane];
        sb[wid][lane] = (lane < K_STEPS - 1) ? (double)BE[lane] : 0.0;
    }
    __syncthreads();
    if (wid < 3) {
        double g = 0.0;
        if (lane < K_STEPS) {
            double bl_ = lane ? sb[wid][lane - 1] : 0.0;
            g = sa[wid][lane] + bl_ + sb[wid][lane];
        }
#pragma unroll
        for (int off = 32; off; off >>= 1) {
            double o = __shfl_xor(g, off, 64);
            if (o > g) g = o;
        }
        double lo = 0.0, hi = g > 0.0 ? g : 1.0;
        for (int round = 0; round < 4; ++round) {
            double step = (hi - lo) / 65.0;
            double x = lo + step * (double)(lane + 1);
            int cnt = 0;
            double d = 1.0;
            for (int i = 0; i < K_STEPS; ++i) {
                double off2 = 0.0;
                if (i) { double b = sb[wid][i - 1]; off2 = b * b / d; }
                d = (sa[wid][i] - x) - off2;
                if (d == 0.0) d = -1e-300;
                if (d < 0.0) cnt++;
            }
            unsigned long long mask = __ballot(cnt >= K_STEPS);
            if (mask) {
                int idx = __ffsll(mask) - 1;
                hi = lo + step * (double)(idx + 1);
                lo = lo + step * (double)idx;
            } else {
                lo = lo + step * 64.0;
            }
        }
        if (lane == 0) {
            double lam = 0.5 * (lo + hi);
            sig[wid] = sqrt(lam > 0.0 ? lam : 0.0);
        }
    }
    __syncthreads();
    if (tid == 0) out[0] = (float)(1e-4 * (sig[0] + sig[1] + sig[2]));
}

extern "C" void kernel_launch(void* const* d_in, const int* in_sizes, int n_in,
                              void* d_out, int out_size, void* d_ws, size_t ws_size,
                              hipStream_t stream) {
    const float* A0 = (const float*)d_in[0];
    const float* A1 = (const float*)d_in[1];
    const float* A2 = (const float*)d_in[2];
    float* out = (float*)d_out;

    const size_t bf_bytes = (size_t)3 * MELEMS * 2;
    const size_t vec_bytes = (size_t)(AOFF + 6 * K_STEPS + 16) * 4;
    bool use_bf = ws_size >= bf_bytes + vec_bytes;

    u16* B = (u16*)d_ws;
    float* vec = use_bf ? (float*)((char*)d_ws + bf_bytes) : (float*)d_ws;

    hipLaunchKernelGGL(k_init, dim3(3), dim3(1024), 0, stream, vec);
    if (use_bf) {
        hipLaunchKernelGGL(k_convert, dim3(2048, 3), dim3(256), 0, stream, A0, A1, A2, B);
        for (int j = 0; j < K_STEPS; ++j) {
            hipLaunchKernelGGL(k_stepA, dim3(3584), dim3(256), 0, stream, B, vec);
            hipLaunchKernelGGL(k_stepT, dim3(384), dim3(256), 0, stream, B, vec);
            hipLaunchKernelGGL(k_redupd, dim3(3), dim3(1024), 0, stream, vec, j);
        }
    } else {
        for (int j = 0; j < K_STEPS; ++j) {
            hipLaunchKernelGGL(k_gemvA, dim3(3584), dim3(256), 0, stream, A0, A1, A2, vec);
            hipLaunchKernelGGL(k_gemvT, dim3(768), dim3(256), 0, stream, A0, A1, A2, vec);
            hipLaunchKernelGGL(k_update, dim3(3), dim3(1024), 0, stream, vec, j);
        }
    }
    hipLaunchKernelGGL(k_final2, dim3(1), dim3(256), 0, stream, vec, out);
}